// Round 7
// baseline (301.588 us; speedup 1.0000x reference)
//
#include <hip/hip_runtime.h>
#include <hip/hip_bf16.h>
#include <cstdint>
#include <cstddef>

#define HDIM 128
#define NLEAVES 65536
#define TOTAL_NODES 131071   // 2*NLEAVES - 1

using s8v  = __attribute__((ext_vector_type(8))) short;
using f4v  = __attribute__((ext_vector_type(4))) float;

__device__ __forceinline__ short f2bf(float f){
  __hip_bfloat16 b = __float2bfloat16(f);
  return *reinterpret_cast<short*>(&b);
}
__device__ __forceinline__ float bf2f(short s){
  unsigned int u = ((unsigned int)(unsigned short)s) << 16;
  return __uint_as_float(u);
}
__device__ __forceinline__ float sigm(float x){ return 1.0f/(1.0f + __expf(-x)); }
__device__ __forceinline__ float tanh_(float x){
  float a = fabsf(x);
  float t = __expf(-2.0f*a);
  float r = (1.0f - t)/(1.0f + t);
  return copysignf(r, x);
}
__device__ __forceinline__ void gload_lds16(const void* g, void* l){
  __builtin_amdgcn_global_load_lds(
      (const __attribute__((address_space(1))) unsigned int*)g,
      (__attribute__((address_space(3))) unsigned int*)l, 16, 0, 0);
}

// ---------------------------------------------------------------------------
// Weight prep.
// Fragment-ready layouts: lane = kg*16 + r16 holds W[g*128+ct*16+r16][kt*32+kg*8+e]
//   Wc_st [8 ct][5 g][8 kt][64 lane][8 e]   (interior, K=256)
//   Wl_st [8 ct][3 g][4 kt][64 lane][8 e]   (leaf,     K=128)
// Wc_lin [640][256] linear (seg/top register weights). bl[384], bc[640].
// ---------------------------------------------------------------------------
__global__ __launch_bounds__(256) void prep_weights(
    const float* __restrict__ Wi, const float* __restrict__ bi,
    const float* __restrict__ Wo, const float* __restrict__ bo,
    const float* __restrict__ Wu, const float* __restrict__ bu,
    const float* __restrict__ Ui, const float* __restrict__ bUi,
    const float* __restrict__ Uo, const float* __restrict__ bUo,
    const float* __restrict__ Uu, const float* __restrict__ bUu,
    const float* __restrict__ F1, const float* __restrict__ bF1,
    const float* __restrict__ F2, const float* __restrict__ bF2,
    short* __restrict__ Wc_lin, short* __restrict__ Wc_st,
    short* __restrict__ Wl_st,
    float* __restrict__ bl, float* __restrict__ bc)
{
  const int gid = blockIdx.x*256 + threadIdx.x;   // 163840
  if (gid < 640*256){
    const int row = gid >> 8, k = gid & 255;
    const int g = row >> 7, jj = row & 127;
    const int ct = jj >> 4, r16 = jj & 15;
    const int kt = k >> 5, kg = (k >> 3) & 3, e = k & 7;
    float v;
    if      (g == 0) v = Ui[jj*256 + k];
    else if (g == 1) v = Uo[jj*256 + k];
    else if (g == 2) v = Uu[jj*256 + k];
    else if (g == 3) v = (k < 128) ? F1[jj*128 + k] : 0.0f;
    else             v = (k >= 128) ? F2[jj*128 + (k-128)] : 0.0f;
    const short s = f2bf(v);
    Wc_lin[gid] = s;
    Wc_st[ct*20480 + (g*8 + kt)*512 + (kg*16 + r16)*8 + e] = s;
  }
  if (gid < 384*128){
    const int row = gid >> 7, k = gid & 127;
    const int g = row >> 7, jj = row & 127;
    const int ct = jj >> 4, r16 = jj & 15;
    const int kt = k >> 5, kg = (k >> 3) & 3, e = k & 7;
    const float v = (g == 0) ? Wi[jj*128 + k] : (g == 1) ? Wo[jj*128 + k] : Wu[jj*128 + k];
    Wl_st[ct*6144 + (g*4 + kt)*512 + (kg*16 + r16)*8 + e] = f2bf(v);
  }
  if (gid < 640){
    const int g = gid >> 7, j = gid & 127;
    bc[gid] = (g==0)?bUi[j]:(g==1)?bUo[j]:(g==2)?bUu[j]:(g==3)?bF1[j]:bF2[j];
  }
  if (gid < 384){
    const int g = gid >> 7, j = gid & 127;
    bl[gid] = (g==0)?bi[j]:(g==1)?bo[j]:bu[j];
  }
}

// ---------------------------------------------------------------------------
// Leaf kernel: 256 thr = 4 waves, 128 nodes/block. B double-buffered (12KB),
// fragment-ready (conflict-free reads). c_out bf16 [8][65536][16].
// ---------------------------------------------------------------------------
__global__ __launch_bounds__(256) void leaf_kernel(
    const int*   __restrict__ tok,
    const float* __restrict__ embed,
    const short* __restrict__ Wst,    // [8][3*4*512]
    const float* __restrict__ bias,   // [384]
    short* __restrict__ h_out,
    short* __restrict__ c_out)
{
  __shared__ short Bst[2][6144];

  const int tid  = threadIdx.x;
  const int lane = tid & 63;
  const int wv   = tid >> 6;
  const int r16  = lane & 15;
  const int kg   = lane >> 4;
  const int m0   = blockIdx.x*128 + wv*32;

  auto stage = [&](int buf, int ct){
    const short* src = Wst + ct*6144;
    #pragma unroll
    for (int i = 0; i < 3; ++i){
      const short* g = src + (size_t)(i*256 + tid)*8;
      short* l = &Bst[buf][0] + (i*256 + wv*64)*8;
      gload_lds16(g, l);
    }
  };

  // A fragments from embed gather
  s8v a[2][4];
  #pragma unroll
  for (int ms = 0; ms < 2; ++ms){
    const int m = m0 + ms*16 + r16;
    const int t = tok[m];
    const float* ep = embed + (size_t)t*HDIM + kg*8;
    #pragma unroll
    for (int kt = 0; kt < 4; ++kt){
      const float4 v0 = *reinterpret_cast<const float4*>(ep + kt*32);
      const float4 v1 = *reinterpret_cast<const float4*>(ep + kt*32 + 4);
      s8v v;
      v[0]=f2bf(v0.x); v[1]=f2bf(v0.y); v[2]=f2bf(v0.z); v[3]=f2bf(v0.w);
      v[4]=f2bf(v1.x); v[5]=f2bf(v1.y); v[6]=f2bf(v1.z); v[7]=f2bf(v1.w);
      a[ms][kt] = v;
    }
  }

  stage(0, 0);
  __syncthreads();

  for (int ct = 0; ct < 8; ++ct){
    const int buf = ct & 1;
    if (ct < 7) stage(buf ^ 1, ct + 1);

    f4v acc[3][2];
    #pragma unroll
    for (int g = 0; g < 3; ++g)
      #pragma unroll
      for (int ms = 0; ms < 2; ++ms)
        #pragma unroll
        for (int e = 0; e < 4; ++e) acc[g][ms][e] = 0.0f;

    #pragma unroll
    for (int g = 0; g < 3; ++g){
      #pragma unroll
      for (int kt = 0; kt < 4; ++kt){
        const s8v b = *reinterpret_cast<const s8v*>(&Bst[buf][(g*4 + kt)*512 + lane*8]);
        acc[g][0] = __builtin_amdgcn_mfma_f32_16x16x32_bf16(a[0][kt], b, acc[g][0], 0, 0, 0);
        acc[g][1] = __builtin_amdgcn_mfma_f32_16x16x32_bf16(a[1][kt], b, acc[g][1], 0, 0, 0);
      }
    }

    const int j = ct*16 + r16;
    const float bi_ = bias[j];
    const float bo_ = bias[HDIM + j];
    const float bu_ = bias[2*HDIM + j];

    #pragma unroll
    for (int ms = 0; ms < 2; ++ms){
      #pragma unroll
      for (int r = 0; r < 4; ++r){
        const int m = m0 + ms*16 + kg*4 + r;
        const float iv = sigm(acc[0][ms][r] + bi_);
        const float ov = sigm(acc[1][ms][r] + bo_);
        const float uv = tanh_(acc[2][ms][r] + bu_);
        const float c  = iv*uv;
        const float hv = ov * tanh_(c);
        c_out[((size_t)ct*NLEAVES + m)*16 + r16] = f2bf(c);
        h_out[(size_t)m*HDIM + j] = f2bf(hv);
      }
    }
    __syncthreads();
  }
}

// ---------------------------------------------------------------------------
// Wide interior level: grid = (M/128)*8; bid&7 = ct. B (40KB) staged once,
// fragment-ready. c bf16 in/out, ct-major [8][*][16].
// ---------------------------------------------------------------------------
__global__ __launch_bounds__(256) void level_ct_kernel(
    const short* __restrict__ A,      // prev h [2M rows][128] = [M][256]
    const short* __restrict__ c_in,   // [8][2M][16] bf16
    const short* __restrict__ Wst,    // [8][5*8*512]
    const float* __restrict__ bias,   // [640]
    short* __restrict__ h_out,        // [M][128]
    short* __restrict__ c_out,        // [8][M][16] bf16
    int M)
{
  __shared__ short Bs[20480];         // 40KB

  const int tid  = threadIdx.x;
  const int bid  = blockIdx.x;
  const int ct   = bid & 7;
  const int mi   = bid >> 3;
  const int lane = tid & 63;
  const int wv   = tid >> 6;
  const int r16  = lane & 15;
  const int kg   = lane >> 4;
  const int m0   = mi*128 + wv*32;

  {
    const short* src = Wst + ct*20480;
    #pragma unroll
    for (int i = 0; i < 10; ++i){
      const short* g = src + (size_t)(i*256 + tid)*8;
      short* l = Bs + (i*256 + wv*64)*8;
      gload_lds16(g, l);
    }
  }

  s8v a[2][8];
  #pragma unroll
  for (int ms = 0; ms < 2; ++ms){
    const short* ap = A + (size_t)(m0 + ms*16 + r16)*256 + kg*8;
    #pragma unroll
    for (int kt = 0; kt < 8; ++kt)
      a[ms][kt] = *reinterpret_cast<const s8v*>(ap + kt*32);
  }
  __syncthreads();

  f4v acc[5][2];
  #pragma unroll
  for (int g = 0; g < 5; ++g)
    #pragma unroll
    for (int ms = 0; ms < 2; ++ms)
      #pragma unroll
      for (int e = 0; e < 4; ++e) acc[g][ms][e] = 0.0f;

  #pragma unroll
  for (int g = 0; g < 5; ++g){
    #pragma unroll
    for (int kt = 0; kt < 8; ++kt){
      const s8v b = *reinterpret_cast<const s8v*>(&Bs[(g*8 + kt)*512 + lane*8]);
      acc[g][0] = __builtin_amdgcn_mfma_f32_16x16x32_bf16(a[0][kt], b, acc[g][0], 0, 0, 0);
      acc[g][1] = __builtin_amdgcn_mfma_f32_16x16x32_bf16(a[1][kt], b, acc[g][1], 0, 0, 0);
    }
  }

  const int j = ct*16 + r16;
  const float bi_  = bias[j];
  const float bo_  = bias[HDIM + j];
  const float bu_  = bias[2*HDIM + j];
  const float bf1_ = bias[3*HDIM + j];
  const float bf2_ = bias[4*HDIM + j];

  #pragma unroll
  for (int ms = 0; ms < 2; ++ms){
    #pragma unroll
    for (int r = 0; r < 4; ++r){
      const int m = m0 + ms*16 + kg*4 + r;
      const float iv = sigm(acc[0][ms][r] + bi_);
      const float ov = sigm(acc[1][ms][r] + bo_);
      const float uv = tanh_(acc[2][ms][r] + bu_);
      const float f1 = sigm(acc[3][ms][r] + bf1_);
      const float f2 = sigm(acc[4][ms][r] + bf2_);
      const float cl = bf2f(c_in[((size_t)ct*(2*M) + 2*m    )*16 + r16]);
      const float cr = bf2f(c_in[((size_t)ct*(2*M) + 2*m + 1)*16 + r16]);
      const float c  = iv*uv + f1*cl + f2*cr;
      const float hv = ov * tanh_(c);
      c_out[((size_t)ct*M + m)*16 + r16] = f2bf(c);
      h_out[(size_t)m*HDIM + j] = f2bf(hv);
    }
  }
}

// ---------------------------------------------------------------------------
// Fused small-level machinery. A kept in fragment-ready LDS (AF), overwritten
// in place by each epilogue. c ping-pongs in LDS fp32 (stride 130, 2-way free).
// CIN: 0 = LDS f32 stride130; 1 = global bf16 ct-major; 2 = global f32 stride128.
// COUT: 0 = LDS f32 stride130; 1 = global f32 stride128.
// ---------------------------------------------------------------------------
template<int N, int CIN, int COUT>
__device__ __forceinline__ void lstm_level(
    const int ct, const int r16, const int kg, const int j,
    const float* __restrict__ cinF, const short* __restrict__ cinB, const int cinCtStride,
    float* coutF, float* __restrict__ coutG,
    short* AF, short* __restrict__ hg,
    const s8v (&biou)[3][8], const s8v (&bf)[2][4],
    const float bi_, const float bo_, const float bu_,
    const float bf1_, const float bf2_)
{
  constexpr int NT = (N > 16) ? 2 : 1;
  const int lane = kg*16 + r16;

  f4v acc[5][NT];
  #pragma unroll
  for (int g = 0; g < 5; ++g)
    #pragma unroll
    for (int mt = 0; mt < NT; ++mt)
      #pragma unroll
      for (int e = 0; e < 4; ++e) acc[g][mt][e] = 0.0f;

  #pragma unroll
  for (int mt = 0; mt < NT; ++mt){
    s8v av[8];
    const short* base = AF + mt*4096 + lane*8;
    #pragma unroll
    for (int kt = 0; kt < 8; ++kt)
      av[kt] = *reinterpret_cast<const s8v*>(base + kt*512);
    #pragma unroll
    for (int kt = 0; kt < 8; ++kt){
      acc[0][mt] = __builtin_amdgcn_mfma_f32_16x16x32_bf16(av[kt], biou[0][kt], acc[0][mt], 0,0,0);
      acc[1][mt] = __builtin_amdgcn_mfma_f32_16x16x32_bf16(av[kt], biou[1][kt], acc[1][mt], 0,0,0);
      acc[2][mt] = __builtin_amdgcn_mfma_f32_16x16x32_bf16(av[kt], biou[2][kt], acc[2][mt], 0,0,0);
    }
    #pragma unroll
    for (int kt = 0; kt < 4; ++kt){
      acc[3][mt] = __builtin_amdgcn_mfma_f32_16x16x32_bf16(av[kt],   bf[0][kt], acc[3][mt], 0,0,0);
      acc[4][mt] = __builtin_amdgcn_mfma_f32_16x16x32_bf16(av[kt+4], bf[1][kt], acc[4][mt], 0,0,0);
    }
  }

  __syncthreads();   // all AF/cin reads complete before overwrite

  #pragma unroll
  for (int mt = 0; mt < NT; ++mt){
    #pragma unroll
    for (int r = 0; r < 4; ++r){
      const int m = mt*16 + kg*4 + r;
      if (m < N){
        const float iv = sigm(acc[0][mt][r] + bi_);
        const float ov = sigm(acc[1][mt][r] + bo_);
        const float uv = tanh_(acc[2][mt][r] + bu_);
        const float f1 = sigm(acc[3][mt][r] + bf1_);
        const float f2 = sigm(acc[4][mt][r] + bf2_);
        float cl, cr;
        if constexpr (CIN == 0){
          cl = cinF[(2*m)*130 + j];   cr = cinF[(2*m+1)*130 + j];
        } else if constexpr (CIN == 1){
          cl = bf2f(cinB[(size_t)ct*cinCtStride + m*32 + r16]);
          cr = bf2f(cinB[(size_t)ct*cinCtStride + m*32 + 16 + r16]);
        } else {
          cl = cinF[(2*m)*128 + j];   cr = cinF[(2*m+1)*128 + j];
        }
        const float c  = iv*uv + f1*cl + f2*cr;
        const float hv = ov * tanh_(c);
        if constexpr (COUT == 0) coutF[m*130 + j] = c;
        else                     coutG[m*128 + j] = c;
        const short hb = f2bf(hv);
        hg[(size_t)m*HDIM + j] = hb;
        // write into next level's A fragment slot
        const int rowp = m >> 1;
        const int kp   = ((m & 1) << 7) | j;
        const int ktp  = kp >> 5;
        const int kgp  = (kp >> 3) & 3;
        AF[(rowp >> 4)*4096 + ktp*512 + ((kgp << 4) | (rowp & 15))*8 + (kp & 7)] = hb;
      }
    }
  }
  __syncthreads();
}

__device__ __forceinline__ void load_reg_weights(
    const short* __restrict__ Wc, const int j, const int kg,
    s8v (&biou)[3][8], s8v (&bf)[2][4])
{
  #pragma unroll
  for (int g = 0; g < 3; ++g){
    const short* bp = Wc + (size_t)(g*128 + j)*256 + kg*8;
    #pragma unroll
    for (int kt = 0; kt < 8; ++kt)
      biou[g][kt] = *reinterpret_cast<const s8v*>(bp + kt*32);
  }
  const short* bp1 = Wc + (size_t)(3*128 + j)*256 + kg*8;
  const short* bp2 = Wc + (size_t)(4*128 + j)*256 + 128 + kg*8;
  #pragma unroll
  for (int kt = 0; kt < 4; ++kt){
    bf[0][kt] = *reinterpret_cast<const s8v*>(bp1 + kt*32);
    bf[1][kt] = *reinterpret_cast<const s8v*>(bp2 + kt*32);
  }
}

// ---------------------------------------------------------------------------
// seg_kernel: 64 blocks; block b computes L5..L10 for its 32 L5-nodes.
// ---------------------------------------------------------------------------
__global__ __launch_bounds__(512, 2) void seg_kernel(
    const short* __restrict__ Wc, const float* __restrict__ bc,
    short* __restrict__ h_all,
    const short* __restrict__ c4,    // [8 ct][4096 nodes][16] bf16 (c of L4)
    float* __restrict__ croot)       // [64][128] f32
{
  __shared__ short AF[8192];        // 2 tiles (32 A-rows x 256)
  __shared__ float cp0[32*130];
  __shared__ float cp1[16*130];

  const int tid  = threadIdx.x;
  const int lane = tid & 63;
  const int ct   = tid >> 6;
  const int r16  = lane & 15;
  const int kg   = lane >> 4;
  const int j    = ct*16 + r16;
  const int b    = blockIdx.x;

  s8v biou[3][8]; s8v bf[2][4];
  load_reg_weights(Wc, j, kg, biou, bf);
  const float bi_ = bc[j], bo_ = bc[HDIM + j], bu_ = bc[2*HDIM + j];
  const float bf1_ = bc[3*HDIM + j], bf2_ = bc[4*HDIM + j];

  // stage A (L4 h rows [64b, 64b+64) -> 32 A-rows, fragment layout)
  const short* h4 = h_all + (size_t)(122880 + 64*b)*HDIM;
  #pragma unroll
  for (int it = 0; it < 2; ++it){
    const int cch = it*512 + tid;
    const int mt = cch >> 9, rem = cch & 511;
    const int kt = rem >> 6, l2 = rem & 63, kg2 = l2 >> 4, r2 = l2 & 15;
    const int rowp = mt*16 + r2;
    const short* src = h4 + (size_t)(2*rowp + (kt>>2))*HDIM + (kt&3)*32 + kg2*8;
    *reinterpret_cast<s8v*>(AF + cch*8) = *reinterpret_cast<const s8v*>(src);
  }
  __syncthreads();

  const short* c4b = c4 + (size_t)b*1024;   // 64 L4-nodes * 16
  lstm_level<32,1,0>(ct,r16,kg,j, nullptr, c4b, 65536, cp0, nullptr, AF,
                     h_all + (size_t)(126976 + 32*b)*HDIM, biou, bf, bi_,bo_,bu_,bf1_,bf2_);
  lstm_level<16,0,0>(ct,r16,kg,j, cp0, nullptr, 0, cp1, nullptr, AF,
                     h_all + (size_t)(129024 + 16*b)*HDIM, biou, bf, bi_,bo_,bu_,bf1_,bf2_);
  lstm_level<8 ,0,0>(ct,r16,kg,j, cp1, nullptr, 0, cp0, nullptr, AF,
                     h_all + (size_t)(130048 + 8*b)*HDIM, biou, bf, bi_,bo_,bu_,bf1_,bf2_);
  lstm_level<4 ,0,0>(ct,r16,kg,j, cp0, nullptr, 0, cp1, nullptr, AF,
                     h_all + (size_t)(130560 + 4*b)*HDIM, biou, bf, bi_,bo_,bu_,bf1_,bf2_);
  lstm_level<2 ,0,0>(ct,r16,kg,j, cp1, nullptr, 0, cp0, nullptr, AF,
                     h_all + (size_t)(130816 + 2*b)*HDIM, biou, bf, bi_,bo_,bu_,bf1_,bf2_);
  lstm_level<1 ,0,1>(ct,r16,kg,j, cp0, nullptr, 0, nullptr, croot + b*HDIM, AF,
                     h_all + (size_t)(130944 + b)*HDIM, biou, bf, bi_,bo_,bu_,bf1_,bf2_);
}

// ---------------------------------------------------------------------------
// top_kernel: 1 block; L11..L16 from the 64 seg roots.
// ---------------------------------------------------------------------------
__global__ __launch_bounds__(512, 2) void top_kernel(
    const short* __restrict__ Wc, const float* __restrict__ bc,
    short* __restrict__ h_all,
    const float* __restrict__ croot)   // [64][128] f32
{
  __shared__ short AF[8192];
  __shared__ float cp0[32*130];
  __shared__ float cp1[16*130];

  const int tid  = threadIdx.x;
  const int lane = tid & 63;
  const int ct   = tid >> 6;
  const int r16  = lane & 15;
  const int kg   = lane >> 4;
  const int j    = ct*16 + r16;

  s8v biou[3][8]; s8v bf[2][4];
  load_reg_weights(Wc, j, kg, biou, bf);
  const float bi_ = bc[j], bo_ = bc[HDIM + j], bu_ = bc[2*HDIM + j];
  const float bf1_ = bc[3*HDIM + j], bf2_ = bc[4*HDIM + j];

  const short* h10 = h_all + (size_t)130944*HDIM;   // 64 rows
  #pragma unroll
  for (int it = 0; it < 2; ++it){
    const int cch = it*512 + tid;
    const int mt = cch >> 9, rem = cch & 511;
    const int kt = rem >> 6, l2 = rem & 63, kg2 = l2 >> 4, r2 = l2 & 15;
    const int rowp = mt*16 + r2;
    const short* src = h10 + (size_t)(2*rowp + (kt>>2))*HDIM + (kt&3)*32 + kg2*8;
    *reinterpret_cast<s8v*>(AF + cch*8) = *reinterpret_cast<const s8v*>(src);
  }
  __syncthreads();

  lstm_level<32,2,0>(ct,r16,kg,j, croot, nullptr, 0, cp0, nullptr, AF,
                     h_all + (size_t)131008*HDIM, biou, bf, bi_,bo_,bu_,bf1_,bf2_);
  lstm_level<16,0,0>(ct,r16,kg,j, cp0, nullptr, 0, cp1, nullptr, AF,
                     h_all + (size_t)131040*HDIM, biou, bf, bi_,bo_,bu_,bf1_,bf2_);
  lstm_level<8 ,0,0>(ct,r16,kg,j, cp1, nullptr, 0, cp0, nullptr, AF,
                     h_all + (size_t)131056*HDIM, biou, bf, bi_,bo_,bu_,bf1_,bf2_);
  lstm_level<4 ,0,0>(ct,r16,kg,j, cp0, nullptr, 0, cp1, nullptr, AF,
                     h_all + (size_t)131064*HDIM, biou, bf, bi_,bo_,bu_,bf1_,bf2_);
  lstm_level<2 ,0,0>(ct,r16,kg,j, cp1, nullptr, 0, cp0, nullptr, AF,
                     h_all + (size_t)131068*HDIM, biou, bf, bi_,bo_,bu_,bf1_,bf2_);
  lstm_level<1 ,0,0>(ct,r16,kg,j, cp0, nullptr, 0, cp1, nullptr, AF,
                     h_all + (size_t)131070*HDIM, biou, bf, bi_,bo_,bu_,bf1_,bf2_);
}

// ---------------------------------------------------------------------------
// Output projection for all nodes + label copy.
// ---------------------------------------------------------------------------
__global__ __launch_bounds__(256) void outproj_kernel(
    const short* __restrict__ h_all,
    const int* __restrict__ labels,
    const float* __restrict__ ow, const float* __restrict__ ob,
    float* __restrict__ out)
{
  __shared__ float wsm[5*HDIM];
  __shared__ float bsm[5];
  for (int i = threadIdx.x; i < 5*HDIM; i += 256) wsm[i] = ow[i];
  if (threadIdx.x < 5) bsm[threadIdx.x] = ob[threadIdx.x];
  __syncthreads();
  const int n = blockIdx.x*256 + threadIdx.x;
  if (n >= TOTAL_NODES) return;
  const s8v* hp = reinterpret_cast<const s8v*>(h_all + (size_t)n*HDIM);
  float acc[5] = {0.f,0.f,0.f,0.f,0.f};
  #pragma unroll
  for (int t = 0; t < 16; ++t){
    const s8v v = hp[t];
    #pragma unroll
    for (int e = 0; e < 8; ++e){
      const float hv = bf2f(v[e]);
      const int jj = t*8 + e;
      #pragma unroll
      for (int c5 = 0; c5 < 5; ++c5) acc[c5] += hv * wsm[c5*HDIM + jj];
    }
  }
  #pragma unroll
  for (int c5 = 0; c5 < 5; ++c5) out[(size_t)n*5 + c5] = acc[c5] + bsm[c5];
  out[(size_t)TOTAL_NODES*5 + n] = (float)labels[n];
}

// ---------------------------------------------------------------------------
extern "C" void kernel_launch(void* const* d_in, const int* in_sizes, int n_in,
                              void* d_out, int out_size, void* d_ws, size_t ws_size,
                              hipStream_t stream)
{
  (void)in_sizes; (void)n_in; (void)out_size; (void)ws_size;
  const int*   tok    = (const int*)  d_in[0];
  const int*   labels = (const int*)  d_in[1];
  const float* embed  = (const float*)d_in[2];
  const float* Wi  = (const float*)d_in[3];  const float* bi  = (const float*)d_in[4];
  const float* Wo  = (const float*)d_in[5];  const float* bo  = (const float*)d_in[6];
  const float* Wu  = (const float*)d_in[7];  const float* bu  = (const float*)d_in[8];
  const float* Ui  = (const float*)d_in[9];  const float* bUi = (const float*)d_in[10];
  const float* Uo  = (const float*)d_in[11]; const float* bUo = (const float*)d_in[12];
  const float* Uu  = (const float*)d_in[13]; const float* bUu = (const float*)d_in[14];
  const float* F1  = (const float*)d_in[15]; const float* bF1 = (const float*)d_in[16];
  const float* F2  = (const float*)d_in[17]; const float* bF2 = (const float*)d_in[18];
  const float* ow  = (const float*)d_in[19]; const float* ob  = (const float*)d_in[20];
  float* out = (float*)d_out;

  char* ws = (char*)d_ws;
  size_t off = 0;
  auto alloc = [&](size_t bytes) -> void* {
    void* p = ws + off;
    off += (bytes + 255) & ~(size_t)255;
    return p;
  };
  short* h_all  = (short*)alloc((size_t)131072*HDIM*2);
  short* c_a    = (short*)alloc((size_t)8*65536*16*2);
  short* c_b    = (short*)alloc((size_t)8*32768*16*2);
  float* croot  = (float*)alloc((size_t)64*HDIM*4);
  short* Wc_lin = (short*)alloc((size_t)640*256*2);
  short* Wc_st  = (short*)alloc((size_t)640*256*2);
  short* Wl_st  = (short*)alloc((size_t)384*128*2);
  float* bl     = (float*)alloc((size_t)384*4);
  float* bc     = (float*)alloc((size_t)640*4);

  prep_weights<<<640, 256, 0, stream>>>(Wi,bi,Wo,bo,Wu,bu,Ui,bUi,Uo,bUo,Uu,bUu,
                                        F1,bF1,F2,bF2, Wc_lin, Wc_st, Wl_st, bl, bc);

  leaf_kernel<<<512, 256, 0, stream>>>(tok, embed, Wl_st, bl, h_all, c_a);

  // L1..L4 wide levels
  level_ct_kernel<<<2048, 256, 0, stream>>>(h_all, c_a, Wc_st, bc,
      h_all + (size_t)65536*HDIM,  c_b, 32768);
  level_ct_kernel<<<1024, 256, 0, stream>>>(h_all + (size_t)65536*HDIM,  c_b, Wc_st, bc,
      h_all + (size_t)98304*HDIM,  c_a, 16384);
  level_ct_kernel<<<512, 256, 0, stream>>>(h_all + (size_t)98304*HDIM,  c_a, Wc_st, bc,
      h_all + (size_t)114688*HDIM, c_b, 8192);
  level_ct_kernel<<<256, 256, 0, stream>>>(h_all + (size_t)114688*HDIM, c_b, Wc_st, bc,
      h_all + (size_t)122880*HDIM, c_a, 4096);

  seg_kernel<<<64, 512, 0, stream>>>(Wc_lin, bc, h_all, c_a, croot);
  top_kernel<<<1, 512, 0, stream>>>(Wc_lin, bc, h_all, croot);

  outproj_kernel<<<(TOTAL_NODES + 255)/256, 256, 0, stream>>>(h_all, labels, ow, ob, out);
}

// Round 9
// 288.929 us; speedup vs baseline: 1.0438x; 1.0438x over previous
//
#include <hip/hip_runtime.h>
#include <hip/hip_bf16.h>
#include <cstdint>
#include <cstddef>

#define HDIM 128
#define NLEAVES 65536
#define TOTAL_NODES 131071   // 2*NLEAVES - 1

using s8v  = __attribute__((ext_vector_type(8))) short;
using f4v  = __attribute__((ext_vector_type(4))) float;

__device__ __forceinline__ short f2bf(float f){
  __hip_bfloat16 b = __float2bfloat16(f);
  return *reinterpret_cast<short*>(&b);
}
__device__ __forceinline__ float bf2f(short s){
  unsigned int u = ((unsigned int)(unsigned short)s) << 16;
  return __uint_as_float(u);
}
__device__ __forceinline__ float sigm(float x){ return 1.0f/(1.0f + __expf(-x)); }
__device__ __forceinline__ float tanh_(float x){
  float a = fabsf(x);
  float t = __expf(-2.0f*a);
  float r = (1.0f - t)/(1.0f + t);
  return copysignf(r, x);
}
__device__ __forceinline__ void gload_lds16(const void* g, void* l){
  __builtin_amdgcn_global_load_lds(
      (const __attribute__((address_space(1))) unsigned int*)g,
      (__attribute__((address_space(3))) unsigned int*)l, 16, 0, 0);
}

// ---------------------------------------------------------------------------
// Weight prep.
// Fragment-ready layouts: lane = kg*16 + r16 holds W[g*128+ct*16+r16][kt*32+kg*8+e]
//   Wc_st [8 ct][5 g][8 kt][64 lane][8 e]   (interior, K=256)
//   Wl_st [8 ct][3 g][4 kt][64 lane][8 e]   (leaf,     K=128)
// Wc_lin [640][256] linear (seg/top register weights). bl[384], bc[640].
// ---------------------------------------------------------------------------
__global__ __launch_bounds__(256) void prep_weights(
    const float* __restrict__ Wi, const float* __restrict__ bi,
    const float* __restrict__ Wo, const float* __restrict__ bo,
    const float* __restrict__ Wu, const float* __restrict__ bu,
    const float* __restrict__ Ui, const float* __restrict__ bUi,
    const float* __restrict__ Uo, const float* __restrict__ bUo,
    const float* __restrict__ Uu, const float* __restrict__ bUu,
    const float* __restrict__ F1, const float* __restrict__ bF1,
    const float* __restrict__ F2, const float* __restrict__ bF2,
    short* __restrict__ Wc_lin, short* __restrict__ Wc_st,
    short* __restrict__ Wl_st,
    float* __restrict__ bl, float* __restrict__ bc)
{
  const int gid = blockIdx.x*256 + threadIdx.x;   // 163840
  if (gid < 640*256){
    const int row = gid >> 8, k = gid & 255;
    const int g = row >> 7, jj = row & 127;
    const int ct = jj >> 4, r16 = jj & 15;
    const int kt = k >> 5, kg = (k >> 3) & 3, e = k & 7;
    float v;
    if      (g == 0) v = Ui[jj*256 + k];
    else if (g == 1) v = Uo[jj*256 + k];
    else if (g == 2) v = Uu[jj*256 + k];
    else if (g == 3) v = (k < 128) ? F1[jj*128 + k] : 0.0f;
    else             v = (k >= 128) ? F2[jj*128 + (k-128)] : 0.0f;
    const short s = f2bf(v);
    Wc_lin[gid] = s;
    Wc_st[ct*20480 + (g*8 + kt)*512 + (kg*16 + r16)*8 + e] = s;
  }
  if (gid < 384*128){
    const int row = gid >> 7, k = gid & 127;
    const int g = row >> 7, jj = row & 127;
    const int ct = jj >> 4, r16 = jj & 15;
    const int kt = k >> 5, kg = (k >> 3) & 3, e = k & 7;
    const float v = (g == 0) ? Wi[jj*128 + k] : (g == 1) ? Wo[jj*128 + k] : Wu[jj*128 + k];
    Wl_st[ct*6144 + (g*4 + kt)*512 + (kg*16 + r16)*8 + e] = f2bf(v);
  }
  if (gid < 640){
    const int g = gid >> 7, j = gid & 127;
    bc[gid] = (g==0)?bUi[j]:(g==1)?bUo[j]:(g==2)?bUu[j]:(g==3)?bF1[j]:bF2[j];
  }
  if (gid < 384){
    const int g = gid >> 7, j = gid & 127;
    bl[gid] = (g==0)?bi[j]:(g==1)?bo[j]:bu[j];
  }
}

// ---------------------------------------------------------------------------
// Leaf kernel: 256 thr = 4 waves, 128 nodes/block. B double-buffered (12KB),
// fragment-ready (conflict-free reads). c_out bf16 [8][65536][16].
// ---------------------------------------------------------------------------
__global__ __launch_bounds__(256) void leaf_kernel(
    const int*   __restrict__ tok,
    const float* __restrict__ embed,
    const short* __restrict__ Wst,    // [8][3*4*512]
    const float* __restrict__ bias,   // [384]
    short* __restrict__ h_out,
    short* __restrict__ c_out)
{
  __shared__ short Bst[2][6144];

  const int tid  = threadIdx.x;
  const int lane = tid & 63;
  const int wv   = tid >> 6;
  const int r16  = lane & 15;
  const int kg   = lane >> 4;
  const int m0   = blockIdx.x*128 + wv*32;

  auto stage = [&](int buf, int ct){
    const short* src = Wst + ct*6144;
    #pragma unroll
    for (int i = 0; i < 3; ++i){
      const short* g = src + (size_t)(i*256 + tid)*8;
      short* l = &Bst[buf][0] + (i*256 + wv*64)*8;
      gload_lds16(g, l);
    }
  };

  // A fragments from embed gather
  s8v a[2][4];
  #pragma unroll
  for (int ms = 0; ms < 2; ++ms){
    const int m = m0 + ms*16 + r16;
    const int t = tok[m];
    const float* ep = embed + (size_t)t*HDIM + kg*8;
    #pragma unroll
    for (int kt = 0; kt < 4; ++kt){
      const float4 v0 = *reinterpret_cast<const float4*>(ep + kt*32);
      const float4 v1 = *reinterpret_cast<const float4*>(ep + kt*32 + 4);
      s8v v;
      v[0]=f2bf(v0.x); v[1]=f2bf(v0.y); v[2]=f2bf(v0.z); v[3]=f2bf(v0.w);
      v[4]=f2bf(v1.x); v[5]=f2bf(v1.y); v[6]=f2bf(v1.z); v[7]=f2bf(v1.w);
      a[ms][kt] = v;
    }
  }

  stage(0, 0);
  __syncthreads();

  for (int ct = 0; ct < 8; ++ct){
    const int buf = ct & 1;
    if (ct < 7) stage(buf ^ 1, ct + 1);

    f4v acc[3][2];
    #pragma unroll
    for (int g = 0; g < 3; ++g)
      #pragma unroll
      for (int ms = 0; ms < 2; ++ms)
        #pragma unroll
        for (int e = 0; e < 4; ++e) acc[g][ms][e] = 0.0f;

    #pragma unroll
    for (int g = 0; g < 3; ++g){
      #pragma unroll
      for (int kt = 0; kt < 4; ++kt){
        const s8v b = *reinterpret_cast<const s8v*>(&Bst[buf][(g*4 + kt)*512 + lane*8]);
        acc[g][0] = __builtin_amdgcn_mfma_f32_16x16x32_bf16(a[0][kt], b, acc[g][0], 0, 0, 0);
        acc[g][1] = __builtin_amdgcn_mfma_f32_16x16x32_bf16(a[1][kt], b, acc[g][1], 0, 0, 0);
      }
    }

    const int j = ct*16 + r16;
    const float bi_ = bias[j];
    const float bo_ = bias[HDIM + j];
    const float bu_ = bias[2*HDIM + j];

    #pragma unroll
    for (int ms = 0; ms < 2; ++ms){
      #pragma unroll
      for (int r = 0; r < 4; ++r){
        const int m = m0 + ms*16 + kg*4 + r;
        const float iv = sigm(acc[0][ms][r] + bi_);
        const float ov = sigm(acc[1][ms][r] + bo_);
        const float uv = tanh_(acc[2][ms][r] + bu_);
        const float c  = iv*uv;
        const float hv = ov * tanh_(c);
        c_out[((size_t)ct*NLEAVES + m)*16 + r16] = f2bf(c);
        h_out[(size_t)m*HDIM + j] = f2bf(hv);
      }
    }
    __syncthreads();
  }
}

// ---------------------------------------------------------------------------
// Wide interior level: grid = 8 * nmi, CT-MAJOR: ct = bid>>mshift,
// mi = bid & (nmi-1). nmi % 8 == 0 so the 8 ct-blocks sharing one A-tile have
// bid % 8 = mi % 8 -> same XCD -> A fetched from HBM once, L2-hit 7 times.
// B (40KB) staged once, fragment-ready. c bf16 in/out, ct-major [8][*][16].
// ---------------------------------------------------------------------------
__global__ __launch_bounds__(256) void level_ct_kernel(
    const short* __restrict__ A,      // prev h [2M rows][128] = [M][256]
    const short* __restrict__ c_in,   // [8][2M][16] bf16
    const short* __restrict__ Wst,    // [8][5*8*512]
    const float* __restrict__ bias,   // [640]
    short* __restrict__ h_out,        // [M][128]
    short* __restrict__ c_out,        // [8][M][16] bf16
    int M, int mshift)
{
  __shared__ short Bs[20480];         // 40KB

  const int tid  = threadIdx.x;
  const int bid  = blockIdx.x;
  const int ct   = bid >> mshift;
  const int mi   = bid & ((1 << mshift) - 1);
  const int lane = tid & 63;
  const int wv   = tid >> 6;
  const int r16  = lane & 15;
  const int kg   = lane >> 4;
  const int m0   = mi*128 + wv*32;

  {
    const short* src = Wst + ct*20480;
    #pragma unroll
    for (int i = 0; i < 10; ++i){
      const short* g = src + (size_t)(i*256 + tid)*8;
      short* l = Bs + (i*256 + wv*64)*8;
      gload_lds16(g, l);
    }
  }

  s8v a[2][8];
  #pragma unroll
  for (int ms = 0; ms < 2; ++ms){
    const short* ap = A + (size_t)(m0 + ms*16 + r16)*256 + kg*8;
    #pragma unroll
    for (int kt = 0; kt < 8; ++kt)
      a[ms][kt] = *reinterpret_cast<const s8v*>(ap + kt*32);
  }
  __syncthreads();

  f4v acc[5][2];
  #pragma unroll
  for (int g = 0; g < 5; ++g)
    #pragma unroll
    for (int ms = 0; ms < 2; ++ms)
      #pragma unroll
      for (int e = 0; e < 4; ++e) acc[g][ms][e] = 0.0f;

  #pragma unroll
  for (int g = 0; g < 5; ++g){
    #pragma unroll
    for (int kt = 0; kt < 8; ++kt){
      const s8v b = *reinterpret_cast<const s8v*>(&Bs[(g*8 + kt)*512 + lane*8]);
      acc[g][0] = __builtin_amdgcn_mfma_f32_16x16x32_bf16(a[0][kt], b, acc[g][0], 0, 0, 0);
      acc[g][1] = __builtin_amdgcn_mfma_f32_16x16x32_bf16(a[1][kt], b, acc[g][1], 0, 0, 0);
    }
  }

  const int j = ct*16 + r16;
  const float bi_  = bias[j];
  const float bo_  = bias[HDIM + j];
  const float bu_  = bias[2*HDIM + j];
  const float bf1_ = bias[3*HDIM + j];
  const float bf2_ = bias[4*HDIM + j];

  #pragma unroll
  for (int ms = 0; ms < 2; ++ms){
    #pragma unroll
    for (int r = 0; r < 4; ++r){
      const int m = m0 + ms*16 + kg*4 + r;
      const float iv = sigm(acc[0][ms][r] + bi_);
      const float ov = sigm(acc[1][ms][r] + bo_);
      const float uv = tanh_(acc[2][ms][r] + bu_);
      const float f1 = sigm(acc[3][ms][r] + bf1_);
      const float f2 = sigm(acc[4][ms][r] + bf2_);
      const float cl = bf2f(c_in[((size_t)ct*(2*M) + 2*m    )*16 + r16]);
      const float cr = bf2f(c_in[((size_t)ct*(2*M) + 2*m + 1)*16 + r16]);
      const float c  = iv*uv + f1*cl + f2*cr;
      const float hv = ov * tanh_(c);
      c_out[((size_t)ct*M + m)*16 + r16] = f2bf(c);
      h_out[(size_t)m*HDIM + j] = f2bf(hv);
    }
  }
}

// ---------------------------------------------------------------------------
// Fused small-level machinery. A kept in fragment-ready LDS (AF), overwritten
// in place by each epilogue. c ping-pongs in LDS fp32 (stride 130, 2-way free).
// CIN: 0 = LDS f32 stride130; 1 = global bf16 ct-major; 2 = global f32 stride128.
// COUT: 0 = LDS f32 stride130; 1 = global f32 stride128.
// ---------------------------------------------------------------------------
template<int N, int CIN, int COUT>
__device__ __forceinline__ void lstm_level(
    const int ct, const int r16, const int kg, const int j,
    const float* __restrict__ cinF, const short* __restrict__ cinB, const int cinCtStride,
    float* coutF, float* __restrict__ coutG,
    short* AF, short* __restrict__ hg,
    const s8v (&biou)[3][8], const s8v (&bf)[2][4],
    const float bi_, const float bo_, const float bu_,
    const float bf1_, const float bf2_)
{
  constexpr int NT = (N > 16) ? 2 : 1;
  const int lane = kg*16 + r16;

  f4v acc[5][NT];
  #pragma unroll
  for (int g = 0; g < 5; ++g)
    #pragma unroll
    for (int mt = 0; mt < NT; ++mt)
      #pragma unroll
      for (int e = 0; e < 4; ++e) acc[g][mt][e] = 0.0f;

  #pragma unroll
  for (int mt = 0; mt < NT; ++mt){
    s8v av[8];
    const short* base = AF + mt*4096 + lane*8;
    #pragma unroll
    for (int kt = 0; kt < 8; ++kt)
      av[kt] = *reinterpret_cast<const s8v*>(base + kt*512);
    #pragma unroll
    for (int kt = 0; kt < 8; ++kt){
      acc[0][mt] = __builtin_amdgcn_mfma_f32_16x16x32_bf16(av[kt], biou[0][kt], acc[0][mt], 0,0,0);
      acc[1][mt] = __builtin_amdgcn_mfma_f32_16x16x32_bf16(av[kt], biou[1][kt], acc[1][mt], 0,0,0);
      acc[2][mt] = __builtin_amdgcn_mfma_f32_16x16x32_bf16(av[kt], biou[2][kt], acc[2][mt], 0,0,0);
    }
    #pragma unroll
    for (int kt = 0; kt < 4; ++kt){
      acc[3][mt] = __builtin_amdgcn_mfma_f32_16x16x32_bf16(av[kt],   bf[0][kt], acc[3][mt], 0,0,0);
      acc[4][mt] = __builtin_amdgcn_mfma_f32_16x16x32_bf16(av[kt+4], bf[1][kt], acc[4][mt], 0,0,0);
    }
  }

  __syncthreads();   // all AF/cin reads complete before overwrite

  #pragma unroll
  for (int mt = 0; mt < NT; ++mt){
    #pragma unroll
    for (int r = 0; r < 4; ++r){
      const int m = mt*16 + kg*4 + r;
      if (m < N){
        const float iv = sigm(acc[0][mt][r] + bi_);
        const float ov = sigm(acc[1][mt][r] + bo_);
        const float uv = tanh_(acc[2][mt][r] + bu_);
        const float f1 = sigm(acc[3][mt][r] + bf1_);
        const float f2 = sigm(acc[4][mt][r] + bf2_);
        float cl, cr;
        if constexpr (CIN == 0){
          cl = cinF[(2*m)*130 + j];   cr = cinF[(2*m+1)*130 + j];
        } else if constexpr (CIN == 1){
          cl = bf2f(cinB[(size_t)ct*cinCtStride + m*32 + r16]);
          cr = bf2f(cinB[(size_t)ct*cinCtStride + m*32 + 16 + r16]);
        } else {
          cl = cinF[(2*m)*128 + j];   cr = cinF[(2*m+1)*128 + j];
        }
        const float c  = iv*uv + f1*cl + f2*cr;
        const float hv = ov * tanh_(c);
        if constexpr (COUT == 0) coutF[m*130 + j] = c;
        else                     coutG[m*128 + j] = c;
        const short hb = f2bf(hv);
        hg[(size_t)m*HDIM + j] = hb;
        // write into next level's A fragment slot
        const int rowp = m >> 1;
        const int kp   = ((m & 1) << 7) | j;
        const int ktp  = kp >> 5;
        const int kgp  = (kp >> 3) & 3;
        AF[(rowp >> 4)*4096 + ktp*512 + ((kgp << 4) | (rowp & 15))*8 + (kp & 7)] = hb;
      }
    }
  }
  __syncthreads();
}

__device__ __forceinline__ void load_reg_weights(
    const short* __restrict__ Wc, const int j, const int kg,
    s8v (&biou)[3][8], s8v (&bf)[2][4])
{
  #pragma unroll
  for (int g = 0; g < 3; ++g){
    const short* bp = Wc + (size_t)(g*128 + j)*256 + kg*8;
    #pragma unroll
    for (int kt = 0; kt < 8; ++kt)
      biou[g][kt] = *reinterpret_cast<const s8v*>(bp + kt*32);
  }
  const short* bp1 = Wc + (size_t)(3*128 + j)*256 + kg*8;
  const short* bp2 = Wc + (size_t)(4*128 + j)*256 + 128 + kg*8;
  #pragma unroll
  for (int kt = 0; kt < 4; ++kt){
    bf[0][kt] = *reinterpret_cast<const s8v*>(bp1 + kt*32);
    bf[1][kt] = *reinterpret_cast<const s8v*>(bp2 + kt*32);
  }
}

// ---------------------------------------------------------------------------
// seg_kernel: 64 blocks; block b computes L5..L10 for its 32 L5-nodes.
// ---------------------------------------------------------------------------
__global__ __launch_bounds__(512, 2) void seg_kernel(
    const short* __restrict__ Wc, const float* __restrict__ bc,
    short* __restrict__ h_all,
    const short* __restrict__ c4,    // [8 ct][4096 nodes][16] bf16 (c of L4)
    float* __restrict__ croot)       // [64][128] f32
{
  __shared__ short AF[8192];        // 2 tiles (32 A-rows x 256)
  __shared__ float cp0[32*130];
  __shared__ float cp1[16*130];

  const int tid  = threadIdx.x;
  const int lane = tid & 63;
  const int ct   = tid >> 6;
  const int r16  = lane & 15;
  const int kg   = lane >> 4;
  const int j    = ct*16 + r16;
  const int b    = blockIdx.x;

  s8v biou[3][8]; s8v bf[2][4];
  load_reg_weights(Wc, j, kg, biou, bf);
  const float bi_ = bc[j], bo_ = bc[HDIM + j], bu_ = bc[2*HDIM + j];
  const float bf1_ = bc[3*HDIM + j], bf2_ = bc[4*HDIM + j];

  // stage A (L4 h rows [64b, 64b+64) -> 32 A-rows, fragment layout)
  const short* h4 = h_all + (size_t)(122880 + 64*b)*HDIM;
  #pragma unroll
  for (int it = 0; it < 2; ++it){
    const int cch = it*512 + tid;
    const int mt = cch >> 9, rem = cch & 511;
    const int kt = rem >> 6, l2 = rem & 63, kg2 = l2 >> 4, r2 = l2 & 15;
    const int rowp = mt*16 + r2;
    const short* src = h4 + (size_t)(2*rowp + (kt>>2))*HDIM + (kt&3)*32 + kg2*8;
    *reinterpret_cast<s8v*>(AF + cch*8) = *reinterpret_cast<const s8v*>(src);
  }
  __syncthreads();

  const short* c4b = c4 + (size_t)b*1024;   // 64 L4-nodes * 16
  lstm_level<32,1,0>(ct,r16,kg,j, nullptr, c4b, 65536, cp0, nullptr, AF,
                     h_all + (size_t)(126976 + 32*b)*HDIM, biou, bf, bi_,bo_,bu_,bf1_,bf2_);
  lstm_level<16,0,0>(ct,r16,kg,j, cp0, nullptr, 0, cp1, nullptr, AF,
                     h_all + (size_t)(129024 + 16*b)*HDIM, biou, bf, bi_,bo_,bu_,bf1_,bf2_);
  lstm_level<8 ,0,0>(ct,r16,kg,j, cp1, nullptr, 0, cp0, nullptr, AF,
                     h_all + (size_t)(130048 + 8*b)*HDIM, biou, bf, bi_,bo_,bu_,bf1_,bf2_);
  lstm_level<4 ,0,0>(ct,r16,kg,j, cp0, nullptr, 0, cp1, nullptr, AF,
                     h_all + (size_t)(130560 + 4*b)*HDIM, biou, bf, bi_,bo_,bu_,bf1_,bf2_);
  lstm_level<2 ,0,0>(ct,r16,kg,j, cp1, nullptr, 0, cp0, nullptr, AF,
                     h_all + (size_t)(130816 + 2*b)*HDIM, biou, bf, bi_,bo_,bu_,bf1_,bf2_);
  lstm_level<1 ,0,1>(ct,r16,kg,j, cp0, nullptr, 0, nullptr, croot + b*HDIM, AF,
                     h_all + (size_t)(130944 + b)*HDIM, biou, bf, bi_,bo_,bu_,bf1_,bf2_);
}

// ---------------------------------------------------------------------------
// top_kernel: 1 block; L11..L16 from the 64 seg roots.
// ---------------------------------------------------------------------------
__global__ __launch_bounds__(512, 2) void top_kernel(
    const short* __restrict__ Wc, const float* __restrict__ bc,
    short* __restrict__ h_all,
    const float* __restrict__ croot)   // [64][128] f32
{
  __shared__ short AF[8192];
  __shared__ float cp0[32*130];
  __shared__ float cp1[16*130];

  const int tid  = threadIdx.x;
  const int lane = tid & 63;
  const int ct   = tid >> 6;
  const int r16  = lane & 15;
  const int kg   = lane >> 4;
  const int j    = ct*16 + r16;

  s8v biou[3][8]; s8v bf[2][4];
  load_reg_weights(Wc, j, kg, biou, bf);
  const float bi_ = bc[j], bo_ = bc[HDIM + j], bu_ = bc[2*HDIM + j];
  const float bf1_ = bc[3*HDIM + j], bf2_ = bc[4*HDIM + j];

  const short* h10 = h_all + (size_t)130944*HDIM;   // 64 rows
  #pragma unroll
  for (int it = 0; it < 2; ++it){
    const int cch = it*512 + tid;
    const int mt = cch >> 9, rem = cch & 511;
    const int kt = rem >> 6, l2 = rem & 63, kg2 = l2 >> 4, r2 = l2 & 15;
    const int rowp = mt*16 + r2;
    const short* src = h10 + (size_t)(2*rowp + (kt>>2))*HDIM + (kt&3)*32 + kg2*8;
    *reinterpret_cast<s8v*>(AF + cch*8) = *reinterpret_cast<const s8v*>(src);
  }
  __syncthreads();

  lstm_level<32,2,0>(ct,r16,kg,j, croot, nullptr, 0, cp0, nullptr, AF,
                     h_all + (size_t)131008*HDIM, biou, bf, bi_,bo_,bu_,bf1_,bf2_);
  lstm_level<16,0,0>(ct,r16,kg,j, cp0, nullptr, 0, cp1, nullptr, AF,
                     h_all + (size_t)131040*HDIM, biou, bf, bi_,bo_,bu_,bf1_,bf2_);
  lstm_level<8 ,0,0>(ct,r16,kg,j, cp1, nullptr, 0, cp0, nullptr, AF,
                     h_all + (size_t)131056*HDIM, biou, bf, bi_,bo_,bu_,bf1_,bf2_);
  lstm_level<4 ,0,0>(ct,r16,kg,j, cp0, nullptr, 0, cp1, nullptr, AF,
                     h_all + (size_t)131064*HDIM, biou, bf, bi_,bo_,bu_,bf1_,bf2_);
  lstm_level<2 ,0,0>(ct,r16,kg,j, cp1, nullptr, 0, cp0, nullptr, AF,
                     h_all + (size_t)131068*HDIM, biou, bf, bi_,bo_,bu_,bf1_,bf2_);
  lstm_level<1 ,0,0>(ct,r16,kg,j, cp0, nullptr, 0, cp1, nullptr, AF,
                     h_all + (size_t)131070*HDIM, biou, bf, bi_,bo_,bu_,bf1_,bf2_);
}

// ---------------------------------------------------------------------------
// Output projection for all nodes + label copy.
// ---------------------------------------------------------------------------
__global__ __launch_bounds__(256) void outproj_kernel(
    const short* __restrict__ h_all,
    const int* __restrict__ labels,
    const float* __restrict__ ow, const float* __restrict__ ob,
    float* __restrict__ out)
{
  __shared__ float wsm[5*HDIM];
  __shared__ float bsm[5];
  for (int i = threadIdx.x; i < 5*HDIM; i += 256) wsm[i] = ow[i];
  if (threadIdx.x < 5) bsm[threadIdx.x] = ob[threadIdx.x];
  __syncthreads();
  const int n = blockIdx.x*256 + threadIdx.x;
  if (n >= TOTAL_NODES) return;
  const s8v* hp = reinterpret_cast<const s8v*>(h_all + (size_t)n*HDIM);
  float acc[5] = {0.f,0.f,0.f,0.f,0.f};
  #pragma unroll
  for (int t = 0; t < 16; ++t){
    const s8v v = hp[t];
    #pragma unroll
    for (int e = 0; e < 8; ++e){
      const float hv = bf2f(v[e]);
      const int jj = t*8 + e;
      #pragma unroll
      for (int c5 = 0; c5 < 5; ++c5) acc[c5] += hv * wsm[c5*HDIM + jj];
    }
  }
  #pragma unroll
  for (int c5 = 0; c5 < 5; ++c5) out[(size_t)n*5 + c5] = acc[c5] + bsm[c5];
  out[(size_t)TOTAL_NODES*5 + n] = (float)labels[n];
}

// ---------------------------------------------------------------------------
extern "C" void kernel_launch(void* const* d_in, const int* in_sizes, int n_in,
                              void* d_out, int out_size, void* d_ws, size_t ws_size,
                              hipStream_t stream)
{
  (void)in_sizes; (void)n_in; (void)out_size; (void)ws_size;
  const int*   tok    = (const int*)  d_in[0];
  const int*   labels = (const int*)  d_in[1];
  const float* embed  = (const float*)d_in[2];
  const float* Wi  = (const float*)d_in[3];  const float* bi  = (const float*)d_in[4];
  const float* Wo  = (const float*)d_in[5];  const float* bo  = (const float*)d_in[6];
  const float* Wu  = (const float*)d_in[7];  const float* bu  = (const float*)d_in[8];
  const float* Ui  = (const float*)d_in[9];  const float* bUi = (const float*)d_in[10];
  const float* Uo  = (const float*)d_in[11]; const float* bUo = (const float*)d_in[12];
  const float* Uu  = (const float*)d_in[13]; const float* bUu = (const float*)d_in[14];
  const float* F1  = (const float*)d_in[15]; const float* bF1 = (const float*)d_in[16];
  const float* F2  = (const float*)d_in[17]; const float* bF2 = (const float*)d_in[18];
  const float* ow  = (const float*)d_in[19]; const float* ob  = (const float*)d_in[20];
  float* out = (float*)d_out;

  char* ws = (char*)d_ws;
  size_t off = 0;
  auto alloc = [&](size_t bytes) -> void* {
    void* p = ws + off;
    off += (bytes + 255) & ~(size_t)255;
    return p;
  };
  short* h_all  = (short*)alloc((size_t)131072*HDIM*2);
  short* c_a    = (short*)alloc((size_t)8*65536*16*2);
  short* c_b    = (short*)alloc((size_t)8*32768*16*2);
  float* croot  = (float*)alloc((size_t)64*HDIM*4);
  short* Wc_lin = (short*)alloc((size_t)640*256*2);
  short* Wc_st  = (short*)alloc((size_t)640*256*2);
  short* Wl_st  = (short*)alloc((size_t)384*128*2);
  float* bl     = (float*)alloc((size_t)384*4);
  float* bc     = (float*)alloc((size_t)640*4);

  prep_weights<<<640, 256, 0, stream>>>(Wi,bi,Wo,bo,Wu,bu,Ui,bUi,Uo,bUo,Uu,bUu,
                                        F1,bF1,F2,bF2, Wc_lin, Wc_st, Wl_st, bl, bc);

  leaf_kernel<<<512, 256, 0, stream>>>(tok, embed, Wl_st, bl, h_all, c_a);

  // L1..L4 wide levels, ct-major grids (nmi = M/128, shift = log2(nmi))
  level_ct_kernel<<<2048, 256, 0, stream>>>(h_all, c_a, Wc_st, bc,
      h_all + (size_t)65536*HDIM,  c_b, 32768, 8);
  level_ct_kernel<<<1024, 256, 0, stream>>>(h_all + (size_t)65536*HDIM,  c_b, Wc_st, bc,
      h_all + (size_t)98304*HDIM,  c_a, 16384, 7);
  level_ct_kernel<<<512, 256, 0, stream>>>(h_all + (size_t)98304*HDIM,  c_a, Wc_st, bc,
      h_all + (size_t)114688*HDIM, c_b, 8192, 6);
  level_ct_kernel<<<256, 256, 0, stream>>>(h_all + (size_t)114688*HDIM, c_b, Wc_st, bc,
      h_all + (size_t)122880*HDIM, c_a, 4096, 5);

  seg_kernel<<<64, 512, 0, stream>>>(Wc_lin, bc, h_all, c_a, croot);
  top_kernel<<<1, 512, 0, stream>>>(Wc_lin, bc, h_all, croot);

  outproj_kernel<<<(TOTAL_NODES + 255)/256, 256, 0, stream>>>(h_all, labels, ow, ob, out);
}

// Round 10
// 267.602 us; speedup vs baseline: 1.1270x; 1.0797x over previous
//
#include <hip/hip_runtime.h>
#include <hip/hip_bf16.h>
#include <cstdint>
#include <cstddef>

#define HDIM 128
#define NLEAVES 65536
#define TOTAL_NODES 131071   // 2*NLEAVES - 1

using s8v  = __attribute__((ext_vector_type(8))) short;
using f4v  = __attribute__((ext_vector_type(4))) float;

__device__ __forceinline__ short f2bf(float f){
  __hip_bfloat16 b = __float2bfloat16(f);
  return *reinterpret_cast<short*>(&b);
}
__device__ __forceinline__ float bf2f(short s){
  unsigned int u = ((unsigned int)(unsigned short)s) << 16;
  return __uint_as_float(u);
}
__device__ __forceinline__ float sigm(float x){ return 1.0f/(1.0f + __expf(-x)); }
__device__ __forceinline__ float tanh_(float x){
  float a = fabsf(x);
  float t = __expf(-2.0f*a);
  float r = (1.0f - t)/(1.0f + t);
  return copysignf(r, x);
}

// ---------------------------------------------------------------------------
// Weight prep (unchanged from round 9; Wc_st written but unused this round).
// Fragment-ready: lane = kg*16 + r16 holds W[g*128+ct*16+r16][kt*32+kg*8+e]
// ---------------------------------------------------------------------------
__global__ __launch_bounds__(256) void prep_weights(
    const float* __restrict__ Wi, const float* __restrict__ bi,
    const float* __restrict__ Wo, const float* __restrict__ bo,
    const float* __restrict__ Wu, const float* __restrict__ bu,
    const float* __restrict__ Ui, const float* __restrict__ bUi,
    const float* __restrict__ Uo, const float* __restrict__ bUo,
    const float* __restrict__ Uu, const float* __restrict__ bUu,
    const float* __restrict__ F1, const float* __restrict__ bF1,
    const float* __restrict__ F2, const float* __restrict__ bF2,
    short* __restrict__ Wc_lin, short* __restrict__ Wc_st,
    short* __restrict__ Wl_st,
    float* __restrict__ bl, float* __restrict__ bc)
{
  const int gid = blockIdx.x*256 + threadIdx.x;   // 163840
  if (gid < 640*256){
    const int row = gid >> 8, k = gid & 255;
    const int g = row >> 7, jj = row & 127;
    const int ct = jj >> 4, r16 = jj & 15;
    const int kt = k >> 5, kg = (k >> 3) & 3, e = k & 7;
    float v;
    if      (g == 0) v = Ui[jj*256 + k];
    else if (g == 1) v = Uo[jj*256 + k];
    else if (g == 2) v = Uu[jj*256 + k];
    else if (g == 3) v = (k < 128) ? F1[jj*128 + k] : 0.0f;
    else             v = (k >= 128) ? F2[jj*128 + (k-128)] : 0.0f;
    const short s = f2bf(v);
    Wc_lin[gid] = s;
    Wc_st[ct*20480 + (g*8 + kt)*512 + (kg*16 + r16)*8 + e] = s;
  }
  if (gid < 384*128){
    const int row = gid >> 7, k = gid & 127;
    const int g = row >> 7, jj = row & 127;
    const int ct = jj >> 4, r16 = jj & 15;
    const int kt = k >> 5, kg = (k >> 3) & 3, e = k & 7;
    const float v = (g == 0) ? Wi[jj*128 + k] : (g == 1) ? Wo[jj*128 + k] : Wu[jj*128 + k];
    Wl_st[ct*6144 + (g*4 + kt)*512 + (kg*16 + r16)*8 + e] = f2bf(v);
  }
  if (gid < 640){
    const int g = gid >> 7, j = gid & 127;
    bc[gid] = (g==0)?bUi[j]:(g==1)?bUo[j]:(g==2)?bUu[j]:(g==3)?bF1[j]:bF2[j];
  }
  if (gid < 384){
    const int g = gid >> 7, j = gid & 127;
    bl[gid] = (g==0)?bi[j]:(g==1)?bo[j]:bu[j];
  }
}

// ---------------------------------------------------------------------------
// One interior LSTM level over AF (fragment-ready A in LDS, in-place update).
// 8 waves = 8 ct slices; weights register-resident.
// CIN: 0 = LDS f32 stride130; 2 = global f32 stride128.
// COUT: 0 = LDS f32 stride130; 1 = global f32 stride128.
// N=64 runs as 2 passes (m in [p*32,p*32+32)); write region (AF mt=p) is
// disjoint from pass-1 read region (AF mt 2..3); barriers separate phases.
// ---------------------------------------------------------------------------
template<int N, int CIN, int COUT>
__device__ __forceinline__ void lstm_level(
    const int ct, const int r16, const int kg, const int j,
    const float* cinF,
    float* coutF, float* __restrict__ coutG,
    short* AF, short* __restrict__ hg,
    const s8v (&biou)[3][8], const s8v (&bf)[2][4],
    const float bi_, const float bo_, const float bu_,
    const float bf1_, const float bf2_)
{
  constexpr int PASSES = (N == 64) ? 2 : 1;
  constexpr int NT     = (N >= 32) ? 2 : 1;
  const int lane = kg*16 + r16;

  #pragma unroll
  for (int p = 0; p < PASSES; ++p){
    f4v acc[5][NT];
    #pragma unroll
    for (int g = 0; g < 5; ++g)
      #pragma unroll
      for (int mt = 0; mt < NT; ++mt)
        #pragma unroll
        for (int e = 0; e < 4; ++e) acc[g][mt][e] = 0.0f;

    #pragma unroll
    for (int mt = 0; mt < NT; ++mt){
      s8v av[8];
      const short* base = AF + (p*2 + mt)*4096 + lane*8;
      #pragma unroll
      for (int kt = 0; kt < 8; ++kt)
        av[kt] = *reinterpret_cast<const s8v*>(base + kt*512);
      #pragma unroll
      for (int kt = 0; kt < 8; ++kt){
        acc[0][mt] = __builtin_amdgcn_mfma_f32_16x16x32_bf16(av[kt], biou[0][kt], acc[0][mt], 0,0,0);
        acc[1][mt] = __builtin_amdgcn_mfma_f32_16x16x32_bf16(av[kt], biou[1][kt], acc[1][mt], 0,0,0);
        acc[2][mt] = __builtin_amdgcn_mfma_f32_16x16x32_bf16(av[kt], biou[2][kt], acc[2][mt], 0,0,0);
      }
      #pragma unroll
      for (int kt = 0; kt < 4; ++kt){
        acc[3][mt] = __builtin_amdgcn_mfma_f32_16x16x32_bf16(av[kt],   bf[0][kt], acc[3][mt], 0,0,0);
        acc[4][mt] = __builtin_amdgcn_mfma_f32_16x16x32_bf16(av[kt+4], bf[1][kt], acc[4][mt], 0,0,0);
      }
    }

    __syncthreads();   // all AF reads of this pass complete before overwrite

    #pragma unroll
    for (int mt = 0; mt < NT; ++mt){
      #pragma unroll
      for (int r = 0; r < 4; ++r){
        const int m = p*32 + mt*16 + kg*4 + r;
        if (m < N){
          const float iv = sigm(acc[0][mt][r] + bi_);
          const float ov = sigm(acc[1][mt][r] + bo_);
          const float uv = tanh_(acc[2][mt][r] + bu_);
          const float f1 = sigm(acc[3][mt][r] + bf1_);
          const float f2 = sigm(acc[4][mt][r] + bf2_);
          float cl, cr;
          if constexpr (CIN == 0){
            cl = cinF[(2*m)*130 + j];   cr = cinF[(2*m+1)*130 + j];
          } else {
            cl = cinF[(2*m)*128 + j];   cr = cinF[(2*m+1)*128 + j];
          }
          const float c  = iv*uv + f1*cl + f2*cr;
          const float hv = ov * tanh_(c);
          if constexpr (COUT == 0) coutF[m*130 + j] = c;
          else                     coutG[m*128 + j] = c;
          const short hb = f2bf(hv);
          hg[(size_t)m*HDIM + j] = hb;
          const int rowp = m >> 1;
          const int kp   = ((m & 1) << 7) | j;
          const int ktp  = kp >> 5;
          const int kgp  = (kp >> 3) & 3;
          AF[(rowp >> 4)*4096 + ktp*512 + ((kgp << 4) | (rowp & 15))*8 + (kp & 7)] = hb;
        }
      }
    }
    __syncthreads();
  }
}

__device__ __forceinline__ void load_reg_weights(
    const short* __restrict__ Wc, const int j, const int kg,
    s8v (&biou)[3][8], s8v (&bf)[2][4])
{
  #pragma unroll
  for (int g = 0; g < 3; ++g){
    const short* bp = Wc + (size_t)(g*128 + j)*256 + kg*8;
    #pragma unroll
    for (int kt = 0; kt < 8; ++kt)
      biou[g][kt] = *reinterpret_cast<const s8v*>(bp + kt*32);
  }
  const short* bp1 = Wc + (size_t)(3*128 + j)*256 + kg*8;
  const short* bp2 = Wc + (size_t)(4*128 + j)*256 + 128 + kg*8;
  #pragma unroll
  for (int kt = 0; kt < 4; ++kt){
    bf[0][kt] = *reinterpret_cast<const s8v*>(bp1 + kt*32);
    bf[1][kt] = *reinterpret_cast<const s8v*>(bp2 + kt*32);
  }
}

// ---------------------------------------------------------------------------
// subtree_kernel: one block = one 128-leaf subtree; leaf + levels L1..L7 all
// in LDS. AF aliases the leaf A buffer (disjoint-region in-place updates).
// ---------------------------------------------------------------------------
__global__ __launch_bounds__(512, 2) void subtree_kernel(
    const int*   __restrict__ tok,
    const float* __restrict__ embed,
    const short* __restrict__ Wl_st,   // [8][3*4*512] fragment-ready
    const short* __restrict__ Wc_lin,  // [640][256]
    const float* __restrict__ bl, const float* __restrict__ bc,
    short* __restrict__ h_all,
    float* __restrict__ croot1)        // [512][128] f32
{
  __shared__ short AF[16384];      // 32KB: leaf [8mt][4kt][64][8] / interior [4mt][8kt][64][8]
  __shared__ float cp0[128*130];   // 66.6KB
  __shared__ float cp1[64*130];    // 33.3KB

  const int tid  = threadIdx.x;
  const int lane = tid & 63;
  const int ct   = tid >> 6;
  const int r16  = lane & 15;
  const int kg   = lane >> 4;
  const int j    = ct*16 + r16;
  const int bid  = blockIdx.x;

  // leaf weights (fragment-ready load)
  s8v wl[3][4];
  #pragma unroll
  for (int g = 0; g < 3; ++g)
    #pragma unroll
    for (int kt = 0; kt < 4; ++kt)
      wl[g][kt] = *reinterpret_cast<const s8v*>(&Wl_st[ct*6144 + (g*4 + kt)*512 + lane*8]);
  const float lbi = bl[j], lbo = bl[HDIM + j], lbu = bl[2*HDIM + j];

  // stage 128 embed rows into leaf fragment layout
  #pragma unroll
  for (int it = 0; it < 4; ++it){
    const int cch = it*512 + tid;           // 2048 chunks of 8
    const int mt = cch >> 8, rem = cch & 255;
    const int kt = rem >> 6, l2 = rem & 63, kg2 = l2 >> 4, r2 = l2 & 15;
    const int row = mt*16 + r2;
    const int t = tok[bid*128 + row];
    const float* ep = embed + (size_t)t*HDIM + kt*32 + kg2*8;
    const float4 v0 = *reinterpret_cast<const float4*>(ep);
    const float4 v1 = *reinterpret_cast<const float4*>(ep + 4);
    s8v v;
    v[0]=f2bf(v0.x); v[1]=f2bf(v0.y); v[2]=f2bf(v0.z); v[3]=f2bf(v0.w);
    v[4]=f2bf(v1.x); v[5]=f2bf(v1.y); v[6]=f2bf(v1.z); v[7]=f2bf(v1.w);
    *reinterpret_cast<s8v*>(AF + mt*2048 + kt*512 + l2*8) = v;
  }
  __syncthreads();

  // leaf level: 2 passes x 4 mt. Pass p reads AF leaf-mt [p*4,p*4+4)
  // (offsets >= p*8192) and writes interior slots rowp in [p*32,p*32+32)
  // (offsets < (p+1)*8192, disjoint from pass-1 reads for p=0).
  #pragma unroll
  for (int p = 0; p < 2; ++p){
    f4v acc[3][4];
    #pragma unroll
    for (int g = 0; g < 3; ++g)
      #pragma unroll
      for (int mt = 0; mt < 4; ++mt)
        #pragma unroll
        for (int e = 0; e < 4; ++e) acc[g][mt][e] = 0.0f;

    #pragma unroll
    for (int mt = 0; mt < 4; ++mt){
      s8v av[4];
      const short* base = AF + (p*4 + mt)*2048 + lane*8;
      #pragma unroll
      for (int kt = 0; kt < 4; ++kt)
        av[kt] = *reinterpret_cast<const s8v*>(base + kt*512);
      #pragma unroll
      for (int kt = 0; kt < 4; ++kt){
        acc[0][mt] = __builtin_amdgcn_mfma_f32_16x16x32_bf16(av[kt], wl[0][kt], acc[0][mt], 0,0,0);
        acc[1][mt] = __builtin_amdgcn_mfma_f32_16x16x32_bf16(av[kt], wl[1][kt], acc[1][mt], 0,0,0);
        acc[2][mt] = __builtin_amdgcn_mfma_f32_16x16x32_bf16(av[kt], wl[2][kt], acc[2][mt], 0,0,0);
      }
    }
    __syncthreads();
    #pragma unroll
    for (int mt = 0; mt < 4; ++mt){
      #pragma unroll
      for (int r = 0; r < 4; ++r){
        const int m = p*64 + mt*16 + kg*4 + r;
        const float iv = sigm(acc[0][mt][r] + lbi);
        const float ov = sigm(acc[1][mt][r] + lbo);
        const float uv = tanh_(acc[2][mt][r] + lbu);
        const float c  = iv*uv;
        const float hv = ov * tanh_(c);
        cp0[m*130 + j] = c;
        const short hb = f2bf(hv);
        h_all[(size_t)(bid*128 + m)*HDIM + j] = hb;
        const int rowp = m >> 1;
        const int kp   = ((m & 1) << 7) | j;
        const int ktp  = kp >> 5;
        const int kgp  = (kp >> 3) & 3;
        AF[(rowp >> 4)*4096 + ktp*512 + ((kgp << 4) | (rowp & 15))*8 + (kp & 7)] = hb;
      }
    }
    __syncthreads();
  }

  // interior weights
  s8v biou[3][8]; s8v bf[2][4];
  load_reg_weights(Wc_lin, j, kg, biou, bf);
  const float bi_ = bc[j], bo_ = bc[HDIM + j], bu_ = bc[2*HDIM + j];
  const float bf1_ = bc[3*HDIM + j], bf2_ = bc[4*HDIM + j];

  lstm_level<64,0,0>(ct,r16,kg,j, cp0, cp1, nullptr, AF, h_all + (size_t)(65536  + bid*64)*HDIM, biou, bf, bi_,bo_,bu_,bf1_,bf2_);
  lstm_level<32,0,0>(ct,r16,kg,j, cp1, cp0, nullptr, AF, h_all + (size_t)(98304  + bid*32)*HDIM, biou, bf, bi_,bo_,bu_,bf1_,bf2_);
  lstm_level<16,0,0>(ct,r16,kg,j, cp0, cp1, nullptr, AF, h_all + (size_t)(114688 + bid*16)*HDIM, biou, bf, bi_,bo_,bu_,bf1_,bf2_);
  lstm_level<8 ,0,0>(ct,r16,kg,j, cp1, cp0, nullptr, AF, h_all + (size_t)(122880 + bid*8 )*HDIM, biou, bf, bi_,bo_,bu_,bf1_,bf2_);
  lstm_level<4 ,0,0>(ct,r16,kg,j, cp0, cp1, nullptr, AF, h_all + (size_t)(126976 + bid*4 )*HDIM, biou, bf, bi_,bo_,bu_,bf1_,bf2_);
  lstm_level<2 ,0,0>(ct,r16,kg,j, cp1, cp0, nullptr, AF, h_all + (size_t)(129024 + bid*2 )*HDIM, biou, bf, bi_,bo_,bu_,bf1_,bf2_);
  lstm_level<1 ,0,1>(ct,r16,kg,j, cp0, nullptr, croot1 + (size_t)bid*HDIM, AF, h_all + (size_t)(130048 + bid)*HDIM, biou, bf, bi_,bo_,bu_,bf1_,bf2_);
}

// ---------------------------------------------------------------------------
// mid_kernel: 4 blocks; block b takes 128 L7-roots -> levels L8..L14.
// ---------------------------------------------------------------------------
__global__ __launch_bounds__(512, 2) void mid_kernel(
    const short* __restrict__ Wc, const float* __restrict__ bc,
    short* __restrict__ h_all,
    const float* __restrict__ croot1,   // [512][128] f32
    float* __restrict__ croot2)         // [4][128] f32
{
  __shared__ short AF[16384];
  __shared__ float cp0[64*130];
  __shared__ float cp1[32*130];

  const int tid  = threadIdx.x;
  const int lane = tid & 63;
  const int ct   = tid >> 6;
  const int r16  = lane & 15;
  const int kg   = lane >> 4;
  const int j    = ct*16 + r16;
  const int b    = blockIdx.x;

  s8v biou[3][8]; s8v bf[2][4];
  load_reg_weights(Wc, j, kg, biou, bf);
  const float bi_ = bc[j], bo_ = bc[HDIM + j], bu_ = bc[2*HDIM + j];
  const float bf1_ = bc[3*HDIM + j], bf2_ = bc[4*HDIM + j];

  // stage 128 L7-root h rows -> 64 A-rows, fragment layout
  const short* h7 = h_all + (size_t)(130048 + b*128)*HDIM;
  #pragma unroll
  for (int it = 0; it < 4; ++it){
    const int cch = it*512 + tid;
    const int mt = cch >> 9, rem = cch & 511;
    const int kt = rem >> 6, l2 = rem & 63, kg2 = l2 >> 4, r2 = l2 & 15;
    const int rowp = mt*16 + r2;
    const short* src = h7 + (size_t)(2*rowp + (kt>>2))*HDIM + (kt&3)*32 + kg2*8;
    *reinterpret_cast<s8v*>(AF + cch*8) = *reinterpret_cast<const s8v*>(src);
  }
  __syncthreads();

  lstm_level<64,2,0>(ct,r16,kg,j, croot1 + (size_t)b*128*HDIM, cp0, nullptr, AF, h_all + (size_t)(130560 + b*64)*HDIM, biou, bf, bi_,bo_,bu_,bf1_,bf2_);
  lstm_level<32,0,0>(ct,r16,kg,j, cp0, cp1, nullptr, AF, h_all + (size_t)(130816 + b*32)*HDIM, biou, bf, bi_,bo_,bu_,bf1_,bf2_);
  lstm_level<16,0,0>(ct,r16,kg,j, cp1, cp0, nullptr, AF, h_all + (size_t)(130944 + b*16)*HDIM, biou, bf, bi_,bo_,bu_,bf1_,bf2_);
  lstm_level<8 ,0,0>(ct,r16,kg,j, cp0, cp1, nullptr, AF, h_all + (size_t)(131008 + b*8 )*HDIM, biou, bf, bi_,bo_,bu_,bf1_,bf2_);
  lstm_level<4 ,0,0>(ct,r16,kg,j, cp1, cp0, nullptr, AF, h_all + (size_t)(131040 + b*4 )*HDIM, biou, bf, bi_,bo_,bu_,bf1_,bf2_);
  lstm_level<2 ,0,0>(ct,r16,kg,j, cp0, cp1, nullptr, AF, h_all + (size_t)(131056 + b*2 )*HDIM, biou, bf, bi_,bo_,bu_,bf1_,bf2_);
  lstm_level<1 ,0,1>(ct,r16,kg,j, cp1, nullptr, croot2 + (size_t)b*HDIM, AF, h_all + (size_t)(131064 + b)*HDIM, biou, bf, bi_,bo_,bu_,bf1_,bf2_);
}

// ---------------------------------------------------------------------------
// top_kernel: 1 block; L15 (N=2) and L16 (N=1) from the 4 mid-roots.
// ---------------------------------------------------------------------------
__global__ __launch_bounds__(512, 2) void top_kernel(
    const short* __restrict__ Wc, const float* __restrict__ bc,
    short* __restrict__ h_all,
    const float* __restrict__ croot2)   // [4][128] f32
{
  __shared__ short AF[4096];     // interior mt=0 tile only
  __shared__ float cp0[2*130];
  __shared__ float cp1[1*130];

  const int tid  = threadIdx.x;
  const int lane = tid & 63;
  const int ct   = tid >> 6;
  const int r16  = lane & 15;
  const int kg   = lane >> 4;
  const int j    = ct*16 + r16;

  s8v biou[3][8]; s8v bf[2][4];
  load_reg_weights(Wc, j, kg, biou, bf);
  const float bi_ = bc[j], bo_ = bc[HDIM + j], bu_ = bc[2*HDIM + j];
  const float bf1_ = bc[3*HDIM + j], bf2_ = bc[4*HDIM + j];

  // stage AF mt=0 fully (rows >=2 get clamped/garbage data; m>=2 discarded)
  if (tid < 512){
    const int cch = tid;
    const int kt = cch >> 6, l2 = cch & 63, kg2 = l2 >> 4, r2 = l2 & 15;
    int hrow = 2*r2 + (kt >> 2);
    if (hrow > 7) hrow = 7;
    const short* src = h_all + (size_t)(131064 + hrow)*HDIM + (kt&3)*32 + kg2*8;
    *reinterpret_cast<s8v*>(AF + kt*512 + l2*8) = *reinterpret_cast<const s8v*>(src);
  }
  __syncthreads();

  lstm_level<2,2,0>(ct,r16,kg,j, croot2, cp0, nullptr, AF, h_all + (size_t)131068*HDIM, biou, bf, bi_,bo_,bu_,bf1_,bf2_);
  lstm_level<1,0,0>(ct,r16,kg,j, cp0, cp1, nullptr, AF, h_all + (size_t)131070*HDIM, biou, bf, bi_,bo_,bu_,bf1_,bf2_);
}

// ---------------------------------------------------------------------------
// Output projection for all nodes + label copy.
// ---------------------------------------------------------------------------
__global__ __launch_bounds__(256) void outproj_kernel(
    const short* __restrict__ h_all,
    const int* __restrict__ labels,
    const float* __restrict__ ow, const float* __restrict__ ob,
    float* __restrict__ out)
{
  __shared__ float wsm[5*HDIM];
  __shared__ float bsm[5];
  for (int i = threadIdx.x; i < 5*HDIM; i += 256) wsm[i] = ow[i];
  if (threadIdx.x < 5) bsm[threadIdx.x] = ob[threadIdx.x];
  __syncthreads();
  const int n = blockIdx.x*256 + threadIdx.x;
  if (n >= TOTAL_NODES) return;
  const s8v* hp = reinterpret_cast<const s8v*>(h_all + (size_t)n*HDIM);
  float acc[5] = {0.f,0.f,0.f,0.f,0.f};
  #pragma unroll
  for (int t = 0; t < 16; ++t){
    const s8v v = hp[t];
    #pragma unroll
    for (int e = 0; e < 8; ++e){
      const float hv = bf2f(v[e]);
      const int jj = t*8 + e;
      #pragma unroll
      for (int c5 = 0; c5 < 5; ++c5) acc[c5] += hv * wsm[c5*HDIM + jj];
    }
  }
  #pragma unroll
  for (int c5 = 0; c5 < 5; ++c5) out[(size_t)n*5 + c5] = acc[c5] + bsm[c5];
  out[(size_t)TOTAL_NODES*5 + n] = (float)labels[n];
}

// ---------------------------------------------------------------------------
extern "C" void kernel_launch(void* const* d_in, const int* in_sizes, int n_in,
                              void* d_out, int out_size, void* d_ws, size_t ws_size,
                              hipStream_t stream)
{
  (void)in_sizes; (void)n_in; (void)out_size; (void)ws_size;
  const int*   tok    = (const int*)  d_in[0];
  const int*   labels = (const int*)  d_in[1];
  const float* embed  = (const float*)d_in[2];
  const float* Wi  = (const float*)d_in[3];  const float* bi  = (const float*)d_in[4];
  const float* Wo  = (const float*)d_in[5];  const float* bo  = (const float*)d_in[6];
  const float* Wu  = (const float*)d_in[7];  const float* bu  = (const float*)d_in[8];
  const float* Ui  = (const float*)d_in[9];  const float* bUi = (const float*)d_in[10];
  const float* Uo  = (const float*)d_in[11]; const float* bUo = (const float*)d_in[12];
  const float* Uu  = (const float*)d_in[13]; const float* bUu = (const float*)d_in[14];
  const float* F1  = (const float*)d_in[15]; const float* bF1 = (const float*)d_in[16];
  const float* F2  = (const float*)d_in[17]; const float* bF2 = (const float*)d_in[18];
  const float* ow  = (const float*)d_in[19]; const float* ob  = (const float*)d_in[20];
  float* out = (float*)d_out;

  char* ws = (char*)d_ws;
  size_t off = 0;
  auto alloc = [&](size_t bytes) -> void* {
    void* p = ws + off;
    off += (bytes + 255) & ~(size_t)255;
    return p;
  };
  short* h_all  = (short*)alloc((size_t)131072*HDIM*2);
  float* croot1 = (float*)alloc((size_t)512*HDIM*4);
  float* croot2 = (float*)alloc((size_t)4*HDIM*4);
  short* Wc_lin = (short*)alloc((size_t)640*256*2);
  short* Wc_st  = (short*)alloc((size_t)640*256*2);
  short* Wl_st  = (short*)alloc((size_t)384*128*2);
  float* bl     = (float*)alloc((size_t)384*4);
  float* bc     = (float*)alloc((size_t)640*4);

  prep_weights<<<640, 256, 0, stream>>>(Wi,bi,Wo,bo,Wu,bu,Ui,bUi,Uo,bUo,Uu,bUu,
                                        F1,bF1,F2,bF2, Wc_lin, Wc_st, Wl_st, bl, bc);

  subtree_kernel<<<512, 512, 0, stream>>>(tok, embed, Wl_st, Wc_lin, bl, bc, h_all, croot1);
  mid_kernel<<<4, 512, 0, stream>>>(Wc_lin, bc, h_all, croot1, croot2);
  top_kernel<<<1, 512, 0, stream>>>(Wc_lin, bc, h_all, croot2);

  outproj_kernel<<<(TOTAL_NODES + 255)/256, 256, 0, stream>>>(h_all, labels, ow, ob, out);
}